// Round 6
// baseline (319.001 us; speedup 1.0000x reference)
//
#include <hip/hip_runtime.h>

// GR4J production-store scan, parallelized by contraction (W=2048 warm-up
// steps recover chunk-entry state; round-4 measured absmax 1.0 vs thr 4.82).
//
// Round-6: VOLATILE register prefetch. Rounds 2/4 showed the compiler sinks
// plain prefetch loads to their use (VGPR_Count=48); round 5's raw-asm loads
// NaN'd (spill/endpgm hazards on asm-held in-flight regs). Volatile loads are
// the middle ground: cannot be sunk/duplicated/rematerialized, result must
// stay live in a register, auto-waitcnt stays fine-grained. No asm, no fence.
//   featurize2     : verbatim round 4 (passed).
//   scan_vol       : 4 rotating volatile-loaded buffers, prefetch distance 3
//                    stages; warm-up (step1, no outputs) and main (stepm)
//                    split at compile time; clamped dead tail prefetch.
//   normalize_stats: finalize folded in (deterministic per-block stat sum).
// Fallback to the round-1 kernel if ws_size too small / odd shapes.

#define L_CHUNK 128
#define WARMUP  2048
#define W_TILES (WARMUP / L_CHUNK)            // 16
#define N_STAGE ((WARMUP + L_CHUNK) / 8)      // 272 stages of 8 steps
#define WU_STAGE (WARMUP / 8)                 // 256 warm-up stages

typedef float f32x4 __attribute__((ext_vector_type(4)));

struct SC { float x1, x1sq, x1_2, c49; };

// warm-up step: state only (outputs removed at compile time)
__device__ __forceinline__ void step1(float& s, float tpx, float tnx, const SC c) {
    float a   = s * tpx;                         // r*tp
    float i   = fmaf(a, a - 1.0f, 1.0f);         // ~1/(1+a)
    float num = tpx * fmaf(-s, s, c.x1sq);       // x1*tp*(1-r^2)
    float w   = c.x1 - s;
    float dd  = tnx * w;                         // (1-r)*tn
    float jj  = fmaf(dd, dd - 1.0f, 1.0f);       // ~1/(1+dd)
    float mm  = (s * tnx) * (c.x1_2 - s);        // s*(2-r)*tn
    float t1  = fmaf(num, i, s);                 // s + p_s
    float s1  = fmaf(-mm, jj, t1);               // s + p_s - e_s
    float z = s1 * c.c49, z2 = z * z, v = z2 * z2;
    float th = fmaf(v, -0.25f, 1.0f);            // (1+v)^-1/4, 1st order
    s = s1 * th;
}

__device__ __forceinline__ void stepm(float& s, float tpx, float tnx, const SC c,
                                      float& ps_o, float& pc_o) {
    float a   = s * tpx;
    float i   = fmaf(a, a - 1.0f, 1.0f);
    float num = tpx * fmaf(-s, s, c.x1sq);
    float w   = c.x1 - s;
    float dd  = tnx * w;
    float jj  = fmaf(dd, dd - 1.0f, 1.0f);
    float mm  = (s * tnx) * (c.x1_2 - s);
    float t1  = fmaf(num, i, s);
    float s1  = fmaf(-mm, jj, t1);
    float z = s1 * c.c49, z2 = z * z, v = z2 * z2;
    float th = fmaf(v, -0.25f, 1.0f);
    float s2 = s1 * th;
    ps_o = num * i;
    pc_o = s1 - s2;
    s = s2;
}

// ---- featurize: verbatim round 4 (coalesced read, LDS transpose, stats) ----
__global__ __launch_bounds__(256) void featurize2(
        const float* __restrict__ x, const float* __restrict__ x1p,
        f32x4* __restrict__ G4, float* __restrict__ partialsB, int Cp) {
    __shared__ f32x4 lx[16 * 65];
    const int col0 = blockIdx.x * 16;
    const int tid  = threadIdx.x;
    const float x1 = x1p[0];
    const float inv = 1.0f / x1;
    float spn = 0.f, sen = 0.f, qpn = 0.f, qen = 0.f;
    const int cl  = tid & 15;
    const int rp0 = tid >> 4;

    if (col0 >= W_TILES) {
        const f32x4* __restrict__ x4 = (const f32x4*)x;
        const size_t base = (size_t)(col0 - W_TILES) * 64;
        #pragma unroll
        for (int k = 0; k < 4; ++k) {
            const int i = tid + 256 * k;
            lx[(i >> 6) * 65 + (i & 63)] = x4[base + i];
        }
        __syncthreads();
        #pragma unroll
        for (int k = 0; k < 4; ++k) {
            const int rp = rp0 + 16 * k;
            f32x4 xv = lx[cl * 65 + rp];           // (P,E,P,E) of 2 steps
            float d0 = xv.x - xv.y, d1 = xv.z - xv.w;
            float pn0 = fmaxf(d0, 0.f), en0 = fmaxf(-d0, 0.f);
            float pn1 = fmaxf(d1, 0.f), en1 = fmaxf(-d1, 0.f);
            float u0 = pn0 * inv, v0 = en0 * inv;
            float u1 = pn1 * inv, v1 = en1 * inv;
            float tpx0 = (u0 * fmaf(u0 * u0, -(1.f/3.f), 1.f)) * inv;
            float tnx0 = (v0 * fmaf(v0 * v0, -(1.f/3.f), 1.f)) * inv;
            float tpx1 = (u1 * fmaf(u1 * u1, -(1.f/3.f), 1.f)) * inv;
            float tnx1 = (v1 * fmaf(v1 * v1, -(1.f/3.f), 1.f)) * inv;
            G4[(size_t)rp * Cp + col0 + cl] = (f32x4){tpx0, tnx0, tpx1, tnx1};
            spn += pn0 + pn1; sen += en0 + en1;
            qpn = fmaf(pn0, pn0, fmaf(pn1, pn1, qpn));
            qen = fmaf(en0, en0, fmaf(en1, en1, qen));
        }
    } else {
        const f32x4 z = (f32x4){0.f, 0.f, 0.f, 0.f};
        #pragma unroll
        for (int k = 0; k < 4; ++k)
            G4[(size_t)(rp0 + 16 * k) * Cp + col0 + cl] = z;
    }

    __shared__ float red[256];
    float vals[4] = {spn, sen, qpn, qen};
    for (int k = 0; k < 4; ++k) {
        red[tid] = vals[k];
        __syncthreads();
        for (int off = 128; off > 0; off >>= 1) {
            if (tid < off) red[tid] += red[tid + off];
            __syncthreads();
        }
        if (tid == 0) partialsB[blockIdx.x * 4 + k] = red[0];
        __syncthreads();
    }
}

// ---- the volatile-prefetch scan ----
__global__ __launch_bounds__(64, 1) void scan_vol(
        const f32x4* __restrict__ G4, const float* __restrict__ x1p,
        f32x4* __restrict__ pspc4, f32x4* __restrict__ s4,
        float* __restrict__ partialsA, int Cp) {
    const int lane  = threadIdx.x;
    const int chunk = blockIdx.x * 64 + lane;
    SC cc;
    cc.x1 = x1p[0]; cc.x1sq = cc.x1 * cc.x1; cc.x1_2 = 2.0f * cc.x1;
    cc.c49 = (4.0f / 9.0f) / cc.x1;

    const volatile f32x4* gvol = (const volatile f32x4*)(G4 + (size_t)blockIdx.x * 64 + lane);
    const size_t cp = (size_t)Cp;

    // volatile load of stage st into q: pinned issue point, result stays live
    auto ld = [&](f32x4 (&q)[4], int st) {
        const int j = st >> 4, sg = st & 15;
        const volatile f32x4* g = gvol + (size_t)(4 * sg) * cp + j;
        q[0] = g[0];
        q[1] = g[cp];
        q[2] = g[2 * cp];
        q[3] = g[3 * cp];
    };

    float s = 0.0f;
    float acc[4] = {0.f, 0.f, 0.f, 0.f};

    // consume buffer (warm-up), then prefetch stage pf into it
    auto wstage = [&](f32x4 (&q)[4], int pf) {
        step1(s, q[0].x, q[0].y, cc); step1(s, q[0].z, q[0].w, cc);
        step1(s, q[1].x, q[1].y, cc); step1(s, q[1].z, q[1].w, cc);
        step1(s, q[2].x, q[2].y, cc); step1(s, q[2].z, q[2].w, cc);
        step1(s, q[3].x, q[3].y, cc); step1(s, q[3].z, q[3].w, cc);
        ld(q, pf);
    };

    auto mstage = [&](f32x4 (&q)[4], int t) {
        float psv[8], pcv[8], sv[8];
        stepm(s, q[0].x, q[0].y, cc, psv[0], pcv[0]); sv[0] = s;
        stepm(s, q[0].z, q[0].w, cc, psv[1], pcv[1]); sv[1] = s;
        stepm(s, q[1].x, q[1].y, cc, psv[2], pcv[2]); sv[2] = s;
        stepm(s, q[1].z, q[1].w, cc, psv[3], pcv[3]); sv[3] = s;
        stepm(s, q[2].x, q[2].y, cc, psv[4], pcv[4]); sv[4] = s;
        stepm(s, q[2].z, q[2].w, cc, psv[5], pcv[5]); sv[5] = s;
        stepm(s, q[3].x, q[3].y, cc, psv[6], pcv[6]); sv[6] = s;
        stepm(s, q[3].z, q[3].w, cc, psv[7], pcv[7]); sv[7] = s;
        const int pf = t + 4;
        ld(q, pf < N_STAGE ? pf : N_STAGE - 1);    // clamped dead tail prefetch (no branch)
        #pragma unroll
        for (int u = 0; u < 8; ++u) {
            acc[0] += psv[u]; acc[1] += pcv[u];
            acc[2] = fmaf(psv[u], psv[u], acc[2]);
            acc[3] = fmaf(pcv[u], pcv[u], acc[3]);
        }
        const int mb = t - WU_STAGE;
        const size_t pb = (size_t)chunk * 64 + 4 * mb;
        pspc4[pb + 0] = (f32x4){psv[0], pcv[0], psv[1], pcv[1]};
        pspc4[pb + 1] = (f32x4){psv[2], pcv[2], psv[3], pcv[3]};
        pspc4[pb + 2] = (f32x4){psv[4], pcv[4], psv[5], pcv[5]};
        pspc4[pb + 3] = (f32x4){psv[6], pcv[6], psv[7], pcv[7]};
        const size_t sb = (size_t)chunk * 32 + 2 * mb;
        s4[sb]     = (f32x4){sv[0], sv[1], sv[2], sv[3]};
        s4[sb + 1] = (f32x4){sv[4], sv[5], sv[6], sv[7]};
    };

    f32x4 A[4], B[4], C[4], D[4];
    ld(A, 0); ld(B, 1); ld(C, 2); ld(D, 3);

    int t = 0;
    #pragma unroll 1
    for (int tb = 0; tb < WU_STAGE / 4; ++tb) {    // stages 0..255
        wstage(A, t + 4);
        wstage(B, t + 5);
        wstage(C, t + 6);
        wstage(D, t + 7);
        t += 4;
    }
    #pragma unroll 1
    for (int tb = 0; tb < (N_STAGE - WU_STAGE) / 4; ++tb) {  // stages 256..271
        mstage(A, t);
        mstage(B, t + 1);
        mstage(C, t + 2);
        mstage(D, t + 3);
        t += 4;
    }

    // ---- wave reduction (block == 1 wave) ----
    #pragma unroll
    for (int k = 0; k < 4; ++k) {
        float v = acc[k];
        #pragma unroll
        for (int off = 32; off > 0; off >>= 1) v += __shfl_down(v, off, 64);
        if (lane == 0) partialsA[blockIdx.x * 4 + k] = v;
    }
}

// ---- finalize folded into normalize: per-block deterministic stat sum ----
__global__ __launch_bounds__(256) void normalize_stats(
        const float* __restrict__ x, const f32x4* __restrict__ pspc4,
        const float* __restrict__ pA, const float* __restrict__ pB,
        f32x4* __restrict__ out4, int nA, int nB, int Thalf, int T) {
    __shared__ float red[256];
    __shared__ float sst[8];
    const int tid = threadIdx.x;
    {   // component c=tid&7: c<4 -> pA (ps,pc,ps2,pc2); c>=4 -> pB (pn,en,pn2,en2)
        const int c = tid & 7;
        const int r0 = tid >> 3;                   // 0..31
        float v = 0.f;
        if (c < 4) { for (int i = r0; i < nA; i += 32) v += pA[i * 4 + c]; }
        else       { for (int i = r0; i < nB; i += 32) v += pB[i * 4 + (c - 4)]; }
        red[tid] = v;
        __syncthreads();
        for (int off = 128; off >= 8; off >>= 1) {
            if (tid < off) red[tid] += red[tid + off];
            __syncthreads();
        }
        if (tid == 0) {
            const float invT = 1.0f / (float)T;
            float su[4] = {red[4], red[5], red[0], red[1]};   // pn,en,ps,pc
            float sq[4] = {red[6], red[7], red[2], red[3]};
            #pragma unroll
            for (int k = 0; k < 4; ++k) {
                float mu  = su[k] * invT;
                float var = fmaxf(fmaf(-mu, mu, sq[k] * invT), 0.0f);
                sst[k]     = mu;
                sst[4 + k] = (var > 0.0f) ? rsqrtf(var) : 0.0f;
            }
        }
        __syncthreads();
    }
    const float mu0 = sst[0], mu1 = sst[1], mu2 = sst[2], mu3 = sst[3];
    const float is0 = sst[4], is1 = sst[5], is2 = sst[6], is3 = sst[7];
    const f32x4* __restrict__ x4 = (const f32x4*)x;
    for (int i = blockIdx.x * 256 + tid; i < Thalf; i += 256 * 256) {
        f32x4 xv = x4[i];
        f32x4 pq = pspc4[i];
        float d0 = xv.x - xv.y, d1 = xv.z - xv.w;
        out4[2 * i]     = (f32x4){(fmaxf(d0, 0.f) - mu0) * is0,
                                  (fmaxf(-d0, 0.f) - mu1) * is1,
                                  (pq.x - mu2) * is2,
                                  (pq.y - mu3) * is3};
        out4[2 * i + 1] = (f32x4){(fmaxf(d1, 0.f) - mu0) * is0,
                                  (fmaxf(-d1, 0.f) - mu1) * is1,
                                  (pq.z - mu2) * is2,
                                  (pq.w - mu3) * is3};
    }
}

// ---------------- round-1 fallback (proven) ----------------
__device__ __forceinline__ float inv1p_fb(float a) {
    float i1 = 1.0f - a;
    float i2 = fmaf(-a, i1, 1.0f);
    return fmaf(-a, i2, 1.0f);
}
struct SCfb { float x1, inv_x1, c49; };
__device__ __forceinline__ void scan_step_fb(float& s, float P, float E, const SCfb c,
                                             float& pn, float& en, float& ps, float& pc) {
    float d = P - E;
    float pn_ = fmaxf(d, 0.0f), en_ = fmaxf(-d, 0.0f);
    float up = pn_ * c.inv_x1;
    float tp = up * fmaf(up * up, -(1.0f / 3.0f), 1.0f);
    float un = en_ * c.inv_x1;
    float tn = un * fmaf(un * un, -(1.0f / 3.0f), 1.0f);
    float r = s * c.inv_x1;
    float ps_ = (tp * c.x1) * fmaf(-r, r, 1.0f) * inv1p_fb(r * tp);
    float es_ = (s * (2.0f - r)) * tn * inv1p_fb((1.0f - r) * tn);
    float s1 = s + ps_ - es_;
    float z = s1 * c.c49, z2 = z * z, v = z2 * z2;
    float t = fmaf(v, fmaf(v, 0.15625f, -0.25f), 1.0f);
    float s2 = s1 * t;
    pn = pn_; en = en_; ps = ps_; pc = s1 - s2; s = s2;
}
__global__ __launch_bounds__(256) void scan_kernel_fb(
        const float* __restrict__ x, const float* __restrict__ x1ptr,
        float* __restrict__ out, float* __restrict__ s_store,
        float* __restrict__ partials, int T) {
    const int c = blockIdx.x * blockDim.x + threadIdx.x;
    const int nchunks = (T + L_CHUNK - 1) / L_CHUNK;
    SCfb cc; cc.x1 = x1ptr[0]; cc.inv_x1 = 1.0f / cc.x1; cc.c49 = (4.0f / 9.0f) * cc.inv_x1;
    float s1a[4] = {0.f, 0.f, 0.f, 0.f};
    float s2a[4] = {0.f, 0.f, 0.f, 0.f};
    if (c < nchunks) {
        const int g0 = c * L_CHUNK;
        const int g1 = min(g0 + L_CHUNK, T);
        const int w0 = max(g0 - WARMUP, 0);
        float s = 0.0f; float pn, en, ps, pc;
        const float2* __restrict__ x2 = (const float2*)x;
        for (int t = w0; t < g0; ++t) { float2 xv = x2[t]; scan_step_fb(s, xv.x, xv.y, cc, pn, en, ps, pc); }
        float4* __restrict__ out4 = (float4*)out;
        for (int t = g0; t < g1; ++t) {
            float2 xv = x2[t];
            scan_step_fb(s, xv.x, xv.y, cc, pn, en, ps, pc);
            out4[t] = make_float4(pn, en, ps, pc);
            s_store[t] = s;
            s1a[0] += pn; s1a[1] += en; s1a[2] += ps; s1a[3] += pc;
            s2a[0] = fmaf(pn, pn, s2a[0]); s2a[1] = fmaf(en, en, s2a[1]);
            s2a[2] = fmaf(ps, ps, s2a[2]); s2a[3] = fmaf(pc, pc, s2a[3]);
        }
    }
    __shared__ float red[256];
    float vals[8] = {s1a[0], s1a[1], s1a[2], s1a[3], s2a[0], s2a[1], s2a[2], s2a[3]};
    for (int k = 0; k < 8; ++k) {
        red[threadIdx.x] = vals[k];
        __syncthreads();
        for (int off = 128; off > 0; off >>= 1) {
            if ((int)threadIdx.x < off) red[threadIdx.x] += red[threadIdx.x + off];
            __syncthreads();
        }
        if (threadIdx.x == 0) partials[blockIdx.x * 8 + k] = red[0];
        __syncthreads();
    }
}
__global__ __launch_bounds__(64) void finalize_fb(
        const float* __restrict__ partials, float* __restrict__ stats, int nblk, int T) {
    const int lane = threadIdx.x;
    float v[8] = {0.f, 0.f, 0.f, 0.f, 0.f, 0.f, 0.f, 0.f};
    for (int b = lane; b < nblk; b += 64)
        for (int k = 0; k < 8; ++k) v[k] += partials[b * 8 + k];
    #pragma unroll
    for (int k = 0; k < 8; ++k)
        for (int off = 32; off > 0; off >>= 1) v[k] += __shfl_down(v[k], off, 64);
    if (lane == 0) {
        const float invT = 1.0f / (float)T;
        for (int k = 0; k < 4; ++k) {
            float mu = v[k] * invT;
            float var = fmaxf(fmaf(-mu, mu, v[k + 4] * invT), 0.0f);
            stats[k] = mu;
            stats[4 + k] = (var > 0.0f) ? rsqrtf(var) : 0.0f;
        }
    }
}
__global__ __launch_bounds__(256) void normalize_fb(
        float* __restrict__ out, const float* __restrict__ stats, int T) {
    const int t = blockIdx.x * blockDim.x + threadIdx.x;
    if (t >= T) return;
    const float4 mu = *(const float4*)stats;
    const float4 is = *(const float4*)(stats + 4);
    float4* o4 = (float4*)out;
    float4 v = o4[t];
    v.x = (v.x - mu.x) * is.x; v.y = (v.y - mu.y) * is.y;
    v.z = (v.z - mu.z) * is.z; v.w = (v.w - mu.w) * is.w;
    o4[t] = v;
}
// -----------------------------------------------------------

extern "C" void kernel_launch(void* const* d_in, const int* in_sizes, int n_in,
                              void* d_out, int out_size, void* d_ws, size_t ws_size,
                              hipStream_t stream) {
    const float* x  = (const float*)d_in[0];
    const float* x1 = (const float*)d_in[1];
    const int T = in_sizes[0] / 2;

    float* out     = (float*)d_out;                // (T,4)
    float* s_store = out + 4 * (size_t)T;          // (T,)
    float* stats   = (float*)d_ws;                 // 8 floats (fallback only)

    const int C  = T / L_CHUNK;                    // chunks
    const int Cp = C + W_TILES;                    // padded columns
    const int nA = C / 64;                         // scan blocks (fast path)
    const int nB = Cp / 16;                        // featurize blocks

    float* pA = stats + 8;                         // nA*4 (<=1024)
    float* pB = pA + 1024;                         // nB*4 (<=4100)
    size_t g4_off = 8 + 1024 + 4100;               // floats
    g4_off = (g4_off + 3) & ~(size_t)3;            // float4 align
    const size_t g4_floats = (size_t)64 * Cp * 4;  // 16.8 MB
    size_t pq_off = g4_off + g4_floats;
    const size_t need = (pq_off + 2 * (size_t)T) * sizeof(float);

    const bool fast = (T % L_CHUNK == 0) && (C % 64 == 0) && (Cp % 16 == 0) &&
                      (T >= WARMUP) && (ws_size >= need);

    if (fast) {
        f32x4* G4    = (f32x4*)((float*)d_ws + g4_off);
        f32x4* pspc4 = (f32x4*)((float*)d_ws + pq_off);
        featurize2<<<nB, 256, 0, stream>>>(x, x1, G4, pB, Cp);
        scan_vol<<<nA, 64, 0, stream>>>(G4, x1, pspc4, (f32x4*)s_store, pA, Cp);
        const int Thalf = T / 2;
        normalize_stats<<<256, 256, 0, stream>>>(x, pspc4, pA, pB,
                                                 (f32x4*)out, nA, nB, Thalf, T);
    } else {
        float* partials = stats + 8;
        const int nchunks = (T + L_CHUNK - 1) / L_CHUNK;
        const int nblkA = (nchunks + 255) / 256;
        scan_kernel_fb<<<nblkA, 256, 0, stream>>>(x, x1, out, s_store, partials, T);
        finalize_fb<<<1, 64, 0, stream>>>(partials, stats, nblkA, T);
        normalize_fb<<<(T + 255) / 256, 256, 0, stream>>>(out, stats, T);
    }
}

// Round 7
// 164.197 us; speedup vs baseline: 1.9428x; 1.9428x over previous
//
#include <hip/hip_runtime.h>

// GR4J production-store scan, parallelized by contraction.
//
// Round-7: LDS-resident feature tile (global memory OFF the scan's critical
// path — rounds 2-6 proved source-level global prefetch is compiler-hostile:
// plain loads get sunk (r4), fences drain (r3), asm corrupts (r5), volatile
// serializes (r6)).
//   scan_fused phase 1: block reads its contiguous x-span coalesced (batched
//     7-deep), computes (tp/x1, tn/x1), writes transposed 64x77 tile to LDS
//     (stride 79 f32x4 -> conflict-free b128). pn/en stats accumulated here.
//   scan_fused phase 2: 224 stages of 8 steps fed ONLY by ds_read_b128 with
//     1-stage double-buffer lookahead (lgkmcnt handling is known-good, m97).
//   Warm-up shortened 2048->1664 by starting at the attractor s0=0.47*x1
//     (initial error ~100 vs 350; final err ~0.9 vs thr 4.82). Chunks < 13
//     keep s0=0 with zero-pad features (exact).
//   normalize_stats: folds the tiny partial-sum reduction, recomputes pn/en
//     from x, assembles (T,4) normalized output. 2 kernels total.
// Fallback to the round-1 kernel (own WARMUP=2048, s0=0) for odd shapes.

#define L_CHUNK  128
#define WARMUP   1664
#define W_TILES  13                        // WARMUP / L_CHUNK
#define SPAN     (64 + W_TILES)            // 77 columns per block tile
#define LDS_STRIDE 79                      // padded stride in f32x4 units
#define N_STAGE  ((WARMUP + L_CHUNK) / 8)  // 224 stages of 8 steps
#define WU_STAGE (WARMUP / 8)              // 208 warm-up stages

typedef float f32x4 __attribute__((ext_vector_type(4)));

struct SC { float x1, x1sq, x1_2, c49; };

// warm-up step: state only (outputs removed at compile time)
__device__ __forceinline__ void step1(float& s, float tpx, float tnx, const SC c) {
    float a   = s * tpx;                         // r*tp
    float i   = fmaf(a, a - 1.0f, 1.0f);         // ~1/(1+a)
    float num = tpx * fmaf(-s, s, c.x1sq);       // x1*tp*(1-r^2)
    float w   = c.x1 - s;
    float dd  = tnx * w;                         // (1-r)*tn
    float jj  = fmaf(dd, dd - 1.0f, 1.0f);       // ~1/(1+dd)
    float mm  = (s * tnx) * (c.x1_2 - s);        // s*(2-r)*tn
    float t1  = fmaf(num, i, s);                 // s + p_s
    float s1  = fmaf(-mm, jj, t1);               // s + p_s - e_s
    float z = s1 * c.c49, z2 = z * z, v = z2 * z2;
    float th = fmaf(v, -0.25f, 1.0f);            // (1+v)^-1/4, 1st order
    s = s1 * th;
}

__device__ __forceinline__ void stepm(float& s, float tpx, float tnx, const SC c,
                                      float& ps_o, float& pc_o) {
    float a   = s * tpx;
    float i   = fmaf(a, a - 1.0f, 1.0f);
    float num = tpx * fmaf(-s, s, c.x1sq);
    float w   = c.x1 - s;
    float dd  = tnx * w;
    float jj  = fmaf(dd, dd - 1.0f, 1.0f);
    float mm  = (s * tnx) * (c.x1_2 - s);
    float t1  = fmaf(num, i, s);
    float s1  = fmaf(-mm, jj, t1);
    float z = s1 * c.c49, z2 = z * z, v = z2 * z2;
    float th = fmaf(v, -0.25f, 1.0f);
    float s2 = s1 * th;
    ps_o = num * i;
    pc_o = s1 - s2;
    s = s2;
}

__global__ __launch_bounds__(64, 1) void scan_fused(
        const float* __restrict__ x, const float* __restrict__ x1p,
        f32x4* __restrict__ pspc4, f32x4* __restrict__ s4,
        float* __restrict__ partials) {
    __shared__ f32x4 tile[64 * LDS_STRIDE];        // 80.9 KB
    const int lane  = threadIdx.x;
    const int b     = blockIdx.x;
    const int chunk = b * 64 + lane;
    const float x1  = x1p[0];
    const float inv = 1.0f / x1;
    SC cc; cc.x1 = x1; cc.x1sq = x1 * x1; cc.x1_2 = 2.0f * x1;
    cc.c49 = (4.0f / 9.0f) * inv;

    // ---- phase 1: coalesced x read -> features -> transposed LDS tile ----
    float spn = 0.f, sen = 0.f, qpn = 0.f, qen = 0.f;
    {
        const f32x4* __restrict__ x4 = (const f32x4*)x;
        const long base4 = (long)b * 4096 - (long)W_TILES * 64;  // f32x4 index
        #pragma unroll 1
        for (int kb = 0; kb < SPAN; kb += 7) {       // 77 = 11*7
            f32x4 xv[7];
            #pragma unroll
            for (int q = 0; q < 7; ++q) {
                const int k = kb + q;
                if (b == 0 && k < W_TILES) xv[q] = (f32x4){0.f, 0.f, 0.f, 0.f};
                else xv[q] = x4[base4 + (long)k * 64 + lane];
            }
            #pragma unroll
            for (int q = 0; q < 7; ++q) {
                const int k = kb + q;
                f32x4 w = xv[q];                     // (P,E,P,E) steps 2*lane,2*lane+1
                float d0 = w.x - w.y, d1 = w.z - w.w;
                float pn0 = fmaxf(d0, 0.f), en0 = fmaxf(-d0, 0.f);
                float pn1 = fmaxf(d1, 0.f), en1 = fmaxf(-d1, 0.f);
                float u0 = pn0 * inv, v0 = en0 * inv;
                float u1 = pn1 * inv, v1 = en1 * inv;
                float tpx0 = (u0 * fmaf(u0 * u0, -(1.f/3.f), 1.f)) * inv;
                float tnx0 = (v0 * fmaf(v0 * v0, -(1.f/3.f), 1.f)) * inv;
                float tpx1 = (u1 * fmaf(u1 * u1, -(1.f/3.f), 1.f)) * inv;
                float tnx1 = (v1 * fmaf(v1 * v1, -(1.f/3.f), 1.f)) * inv;
                tile[lane * LDS_STRIDE + k] = (f32x4){tpx0, tnx0, tpx1, tnx1};
                if (k >= W_TILES) {                  // block's own chunks only
                    spn += pn0 + pn1; sen += en0 + en1;
                    qpn = fmaf(pn0, pn0, fmaf(pn1, pn1, qpn));
                    qen = fmaf(en0, en0, fmaf(en1, en1, qen));
                }
            }
        }
    }
    __syncthreads();

    // ---- phase 2: LDS-fed scan, 1-stage double-buffer lookahead ----
    // chunks >= W_TILES: full real warm-up, start at attractor 0.47*x1.
    // chunks <  W_TILES: zero-pad prefix (exact), must start at true s0=0.
    float s = (chunk >= W_TILES) ? 0.47f * x1 : 0.0f;
    float aps = 0.f, apc = 0.f, qps = 0.f, qpc = 0.f;

    auto rdst = [&](f32x4 (&q)[4], int st) {
        const int j = st >> 4, rp0 = 4 * (st & 15);
        const int base = lane + j;
        #pragma unroll
        for (int u = 0; u < 4; ++u) q[u] = tile[(rp0 + u) * LDS_STRIDE + base];
    };
    auto wst = [&](f32x4 (&q)[4]) {
        #pragma unroll
        for (int u = 0; u < 4; ++u) {
            step1(s, q[u].x, q[u].y, cc);
            step1(s, q[u].z, q[u].w, cc);
        }
    };
    auto mst = [&](f32x4 (&q)[4], int st) {
        float psv[8], pcv[8], sv[8];
        #pragma unroll
        for (int u = 0; u < 4; ++u) {
            stepm(s, q[u].x, q[u].y, cc, psv[2*u],   pcv[2*u]);   sv[2*u]   = s;
            stepm(s, q[u].z, q[u].w, cc, psv[2*u+1], pcv[2*u+1]); sv[2*u+1] = s;
        }
        #pragma unroll
        for (int u = 0; u < 8; ++u) {
            aps += psv[u]; apc += pcv[u];
            qps = fmaf(psv[u], psv[u], qps); qpc = fmaf(pcv[u], pcv[u], qpc);
        }
        const int mb = st - WU_STAGE;
        const size_t pb = (size_t)chunk * 64 + 4 * mb;
        pspc4[pb + 0] = (f32x4){psv[0], pcv[0], psv[1], pcv[1]};
        pspc4[pb + 1] = (f32x4){psv[2], pcv[2], psv[3], pcv[3]};
        pspc4[pb + 2] = (f32x4){psv[4], pcv[4], psv[5], pcv[5]};
        pspc4[pb + 3] = (f32x4){psv[6], pcv[6], psv[7], pcv[7]};
        const size_t sb = (size_t)chunk * 32 + 2 * mb;
        s4[sb]     = (f32x4){sv[0], sv[1], sv[2], sv[3]};
        s4[sb + 1] = (f32x4){sv[4], sv[5], sv[6], sv[7]};
    };

    f32x4 P[4], Q[4];
    rdst(P, 0);
    #pragma unroll 1
    for (int st = 0; st < WU_STAGE; st += 2) {       // stages 0..207
        rdst(Q, st + 1);
        wst(P);
        rdst(P, st + 2);                             // st+2 <= 208 < 224: valid
        wst(Q);
    }
    #pragma unroll 1
    for (int st = WU_STAGE; st < N_STAGE; st += 2) { // stages 208..223
        rdst(Q, st + 1);
        mst(P, st);
        rdst(P, st + 2 < N_STAGE ? st + 2 : N_STAGE - 1);  // clamped dead read
        mst(Q, st + 1);
    }

    // ---- wave reduction (block == 1 wave) of 8 stat accumulators ----
    float vals[8] = {spn, sen, aps, apc, qpn, qen, qps, qpc};
    #pragma unroll
    for (int k = 0; k < 8; ++k) {
        float v = vals[k];
        #pragma unroll
        for (int off = 32; off > 0; off >>= 1) v += __shfl_down(v, off, 64);
        if (lane == 0) partials[b * 8 + k] = v;
    }
}

// ---- stats finalize folded in + fused normalize/assemble ----
__global__ __launch_bounds__(256) void normalize_stats(
        const float* __restrict__ x, const f32x4* __restrict__ pspc4,
        const float* __restrict__ pA, f32x4* __restrict__ out4,
        int nA, int Thalf, int T) {
    __shared__ float red[256];
    __shared__ float sst[8];
    const int tid = threadIdx.x;
    {   // components: 0 pn,1 en,2 ps,3 pc (sums); 4..7 squares
        const int c = tid & 7;
        float v = 0.f;
        for (int i = tid >> 3; i < nA; i += 32) v += pA[i * 8 + c];
        red[tid] = v;
        __syncthreads();
        for (int off = 128; off >= 8; off >>= 1) {
            if (tid < off) red[tid] += red[tid + off];
            __syncthreads();
        }
        if (tid == 0) {
            const float invT = 1.0f / (float)T;
            #pragma unroll
            for (int k = 0; k < 4; ++k) {
                float mu  = red[k] * invT;
                float var = fmaxf(fmaf(-mu, mu, red[4 + k] * invT), 0.0f);
                sst[k]     = mu;
                sst[4 + k] = (var > 0.0f) ? rsqrtf(var) : 0.0f;
            }
        }
        __syncthreads();
    }
    const float mu0 = sst[0], mu1 = sst[1], mu2 = sst[2], mu3 = sst[3];
    const float is0 = sst[4], is1 = sst[5], is2 = sst[6], is3 = sst[7];
    const f32x4* __restrict__ x4 = (const f32x4*)x;
    for (int i = blockIdx.x * 256 + tid; i < Thalf; i += 1024 * 256) {
        f32x4 xv = x4[i];
        f32x4 pq = pspc4[i];
        float d0 = xv.x - xv.y, d1 = xv.z - xv.w;
        out4[2 * i]     = (f32x4){(fmaxf(d0, 0.f) - mu0) * is0,
                                  (fmaxf(-d0, 0.f) - mu1) * is1,
                                  (pq.x - mu2) * is2,
                                  (pq.y - mu3) * is3};
        out4[2 * i + 1] = (f32x4){(fmaxf(d1, 0.f) - mu0) * is0,
                                  (fmaxf(-d1, 0.f) - mu1) * is1,
                                  (pq.z - mu2) * is2,
                                  (pq.w - mu3) * is3};
    }
}

// ---------------- round-1 fallback (proven; own WARMUP=2048, s0=0) ----------
#define FB_WARMUP 2048
__device__ __forceinline__ float inv1p_fb(float a) {
    float i1 = 1.0f - a;
    float i2 = fmaf(-a, i1, 1.0f);
    return fmaf(-a, i2, 1.0f);
}
struct SCfb { float x1, inv_x1, c49; };
__device__ __forceinline__ void scan_step_fb(float& s, float P, float E, const SCfb c,
                                             float& pn, float& en, float& ps, float& pc) {
    float d = P - E;
    float pn_ = fmaxf(d, 0.0f), en_ = fmaxf(-d, 0.0f);
    float up = pn_ * c.inv_x1;
    float tp = up * fmaf(up * up, -(1.0f / 3.0f), 1.0f);
    float un = en_ * c.inv_x1;
    float tn = un * fmaf(un * un, -(1.0f / 3.0f), 1.0f);
    float r = s * c.inv_x1;
    float ps_ = (tp * c.x1) * fmaf(-r, r, 1.0f) * inv1p_fb(r * tp);
    float es_ = (s * (2.0f - r)) * tn * inv1p_fb((1.0f - r) * tn);
    float s1 = s + ps_ - es_;
    float z = s1 * c.c49, z2 = z * z, v = z2 * z2;
    float t = fmaf(v, fmaf(v, 0.15625f, -0.25f), 1.0f);
    float s2 = s1 * t;
    pn = pn_; en = en_; ps = ps_; pc = s1 - s2; s = s2;
}
__global__ __launch_bounds__(256) void scan_kernel_fb(
        const float* __restrict__ x, const float* __restrict__ x1ptr,
        float* __restrict__ out, float* __restrict__ s_store,
        float* __restrict__ partials, int T) {
    const int c = blockIdx.x * blockDim.x + threadIdx.x;
    const int nchunks = (T + L_CHUNK - 1) / L_CHUNK;
    SCfb cc; cc.x1 = x1ptr[0]; cc.inv_x1 = 1.0f / cc.x1; cc.c49 = (4.0f / 9.0f) * cc.inv_x1;
    float s1a[4] = {0.f, 0.f, 0.f, 0.f};
    float s2a[4] = {0.f, 0.f, 0.f, 0.f};
    if (c < nchunks) {
        const int g0 = c * L_CHUNK;
        const int g1 = min(g0 + L_CHUNK, T);
        const int w0 = max(g0 - FB_WARMUP, 0);
        float s = 0.0f; float pn, en, ps, pc;
        const float2* __restrict__ x2 = (const float2*)x;
        for (int t = w0; t < g0; ++t) { float2 xv = x2[t]; scan_step_fb(s, xv.x, xv.y, cc, pn, en, ps, pc); }
        float4* __restrict__ out4 = (float4*)out;
        for (int t = g0; t < g1; ++t) {
            float2 xv = x2[t];
            scan_step_fb(s, xv.x, xv.y, cc, pn, en, ps, pc);
            out4[t] = make_float4(pn, en, ps, pc);
            s_store[t] = s;
            s1a[0] += pn; s1a[1] += en; s1a[2] += ps; s1a[3] += pc;
            s2a[0] = fmaf(pn, pn, s2a[0]); s2a[1] = fmaf(en, en, s2a[1]);
            s2a[2] = fmaf(ps, ps, s2a[2]); s2a[3] = fmaf(pc, pc, s2a[3]);
        }
    }
    __shared__ float red[256];
    float vals[8] = {s1a[0], s1a[1], s1a[2], s1a[3], s2a[0], s2a[1], s2a[2], s2a[3]};
    for (int k = 0; k < 8; ++k) {
        red[threadIdx.x] = vals[k];
        __syncthreads();
        for (int off = 128; off > 0; off >>= 1) {
            if ((int)threadIdx.x < off) red[threadIdx.x] += red[threadIdx.x + off];
            __syncthreads();
        }
        if (threadIdx.x == 0) partials[blockIdx.x * 8 + k] = red[0];
        __syncthreads();
    }
}
__global__ __launch_bounds__(64) void finalize_fb(
        const float* __restrict__ partials, float* __restrict__ stats, int nblk, int T) {
    const int lane = threadIdx.x;
    float v[8] = {0.f, 0.f, 0.f, 0.f, 0.f, 0.f, 0.f, 0.f};
    for (int b = lane; b < nblk; b += 64)
        for (int k = 0; k < 8; ++k) v[k] += partials[b * 8 + k];
    #pragma unroll
    for (int k = 0; k < 8; ++k)
        for (int off = 32; off > 0; off >>= 1) v[k] += __shfl_down(v[k], off, 64);
    if (lane == 0) {
        const float invT = 1.0f / (float)T;
        for (int k = 0; k < 4; ++k) {
            float mu = v[k] * invT;
            float var = fmaxf(fmaf(-mu, mu, v[k + 4] * invT), 0.0f);
            stats[k] = mu;
            stats[4 + k] = (var > 0.0f) ? rsqrtf(var) : 0.0f;
        }
    }
}
__global__ __launch_bounds__(256) void normalize_fb(
        float* __restrict__ out, const float* __restrict__ stats, int T) {
    const int t = blockIdx.x * blockDim.x + threadIdx.x;
    if (t >= T) return;
    const float4 mu = *(const float4*)stats;
    const float4 is = *(const float4*)(stats + 4);
    float4* o4 = (float4*)out;
    float4 v = o4[t];
    v.x = (v.x - mu.x) * is.x; v.y = (v.y - mu.y) * is.y;
    v.z = (v.z - mu.z) * is.z; v.w = (v.w - mu.w) * is.w;
    o4[t] = v;
}
// -----------------------------------------------------------------------------

extern "C" void kernel_launch(void* const* d_in, const int* in_sizes, int n_in,
                              void* d_out, int out_size, void* d_ws, size_t ws_size,
                              hipStream_t stream) {
    const float* x  = (const float*)d_in[0];
    const float* x1 = (const float*)d_in[1];
    const int T = in_sizes[0] / 2;

    float* out     = (float*)d_out;                // (T,4)
    float* s_store = out + 4 * (size_t)T;          // (T,)

    const int C  = T / L_CHUNK;                    // chunks
    const int nA = C / 64;                         // scan blocks (fast path)

    float* pA = (float*)d_ws;                      // nA*8 floats (<=2048)
    const size_t pq_off = 2048;                    // f32x4-aligned float offset
    const size_t need = (pq_off + 2 * (size_t)T) * sizeof(float);

    const bool fast = (T % L_CHUNK == 0) && (C % 64 == 0) &&
                      (T >= WARMUP + L_CHUNK) && (ws_size >= need);

    if (fast) {
        f32x4* pspc4 = (f32x4*)((float*)d_ws + pq_off);
        scan_fused<<<nA, 64, 0, stream>>>(x, x1, pspc4, (f32x4*)s_store, pA);
        const int Thalf = T / 2;
        normalize_stats<<<1024, 256, 0, stream>>>(x, pspc4, pA,
                                                  (f32x4*)out, nA, Thalf, T);
    } else {
        float* stats    = (float*)d_ws;
        float* partials = stats + 8;
        const int nchunks = (T + L_CHUNK - 1) / L_CHUNK;
        const int nblkA = (nchunks + 255) / 256;
        scan_kernel_fb<<<nblkA, 256, 0, stream>>>(x, x1, out, s_store, partials, T);
        finalize_fb<<<1, 64, 0, stream>>>(partials, stats, nblkA, T);
        normalize_fb<<<(T + 255) / 256, 256, 0, stream>>>(out, stats, T);
    }
}

// Round 8
// 137.454 us; speedup vs baseline: 2.3208x; 1.1946x over previous
//
#include <hip/hip_runtime.h>

// GR4J production-store scan, parallelized by contraction.
//
// Round-8: cubic-polynomial step. r7 post-mortem: per-step cost ~118 cyc both
// with LDS (r7) and exposed-global (r4) feeds => the scan is dependent-chain
// latency-bound (~10 VALU levels x ~12 cyc lone-wave dep latency). Fix:
// precompute per-step cubic coefficients (2nd-order denominators expanded,
// quartic terms <= 0.004 dropped) in phase 1, so one step is
//   s1 = fmaf(s^2, fmaf(k3,s,k2), fmaf(k1,s,k0));  s' = s1 - gma*s1^5
// = 5 chained levels, 8 VALU. Outputs need no extra storage: pn/en are
// mutually exclusive => ps == relu(s1 - s) exactly; pc = gma*s1^5.
// W shortened 1664->1408 (attractor start, residual err ~0.003..0.9 vs 4.82).
// LDS tile: 128 rows x 75 cols x 16B = 153.6 KB (fits 160 KB; r7 proved >64KB ok).
// Fallback to the round-1 kernel for odd shapes.

#define L_CHUNK  128
#define W_TILES  11
#define WARMUP   (W_TILES * L_CHUNK)       // 1408
#define SPAN     (64 + W_TILES)            // 75 columns per block tile
#define N_STAGE  ((WARMUP + L_CHUNK) / 8)  // 192 stages of 8 steps
#define WU_STAGE (WARMUP / 8)              // 176 warm-up stages

typedef float f32x4 __attribute__((ext_vector_type(4)));

// one cubic step, warm-up flavor (state only)
__device__ __forceinline__ void stepk(float& s, const f32x4 k, float gma) {
    float s2m = s * s;
    float t1  = fmaf(k.y, s, k.x);
    float t2  = fmaf(k.w, s, k.z);
    float s1  = fmaf(s2m, t2, t1);
    float w2  = s1 * s1;
    float q4  = gma * s1;
    float w4  = w2 * w2;
    s = fmaf(-q4, w4, s1);
}

// main flavor: also emit ps (= relu(s1 - s_prev), exact) and pc (= gma*s1^5)
__device__ __forceinline__ void stepk_m(float& s, const f32x4 k, float gma,
                                        float& ps_o, float& pc_o) {
    float sp  = s;
    float s2m = s * s;
    float t1  = fmaf(k.y, s, k.x);
    float t2  = fmaf(k.w, s, k.z);
    float s1  = fmaf(s2m, t2, t1);
    float w2  = s1 * s1;
    float q4  = gma * s1;
    float w4  = w2 * w2;
    s = fmaf(-q4, w4, s1);
    ps_o = fmaxf(s1 - sp, 0.0f);
    pc_o = q4 * w4;
}

__global__ __launch_bounds__(64, 1) void scan_poly(
        const float* __restrict__ x, const float* __restrict__ x1p,
        f32x4* __restrict__ pspc4, f32x4* __restrict__ s4,
        float* __restrict__ partials) {
    __shared__ f32x4 tile[128 * SPAN];             // 153.6 KB
    const int lane  = threadIdx.x;
    const int b     = blockIdx.x;
    const int chunk = b * 64 + lane;
    const float x1  = x1p[0];
    const float inv = 1.0f / x1;
    const float x1sq = x1 * x1;
    const float x1_2 = 2.0f * x1;
    const float two_x1cu  = 2.0f * x1 * x1sq;
    const float five_x1sq = 5.0f * x1sq;
    const float four_x1   = 4.0f * x1;
    const float gma = 64.0f / (6561.0f * x1sq * x1sq);   // perc = gma*s1^5

    // ---- phase 1: coalesced x read -> cubic coeffs -> transposed LDS tile ----
    float spn = 0.f, sen = 0.f, qpn = 0.f, qen = 0.f;
    {
        const f32x4* __restrict__ x4 = (const f32x4*)x;
        const long base4 = (long)b * 4096 - (long)(W_TILES * 64);  // f32x4 index
        #pragma unroll 1
        for (int kb = 0; kb < SPAN; kb += 5) {       // 75 = 15*5
            f32x4 xv[5];
            #pragma unroll
            for (int q = 0; q < 5; ++q) {
                const long gi = base4 + (long)(kb + q) * 64 + lane;
                xv[q] = (gi >= 0) ? x4[gi] : (f32x4){0.f, 0.f, 0.f, 0.f};
            }
            #pragma unroll
            for (int q = 0; q < 5; ++q) {
                const int k = kb + q;
                const f32x4 w = xv[q];               // (P,E,P,E): steps 2*lane, 2*lane+1
                #pragma unroll
                for (int h = 0; h < 2; ++h) {
                    const float P  = h ? w.z : w.x;
                    const float Ev = h ? w.w : w.y;
                    float d  = P - Ev;
                    float pn = fmaxf(d, 0.f), en = fmaxf(-d, 0.f);
                    float up = pn * inv, un = en * inv;
                    float tp = up * fmaf(up * up, -(1.f/3.f), 1.f);
                    float tn = un * fmaf(un * un, -(1.f/3.f), 1.f);
                    float al = tp * inv, be = tn * inv;
                    float a2 = al * al,  a3v = a2 * al;
                    float b2 = be * be,  b3v = b2 * be;
                    float e2 = fmaf(-be, x1, 1.f);
                    float k0 = tp * x1;                               // al*x1^2
                    float k1 = 1.f - a2 * x1sq
                             - (x1_2 * be * e2 + two_x1cu * b3v);
                    float k2 = (a3v * x1sq - al)
                             - (x1_2 * b2 - be * e2 - five_x1sq * b3v);
                    float k3 = a2 + b2 - four_x1 * b3v;
                    tile[(2 * lane + h) * SPAN + k] = (f32x4){k0, k1, k2, k3};
                    if (k >= W_TILES) {              // block's own chunks only
                        spn += pn; sen += en;
                        qpn = fmaf(pn, pn, qpn); qen = fmaf(en, en, qen);
                    }
                }
            }
        }
    }
    __syncthreads();

    // ---- phase 2: LDS-fed cubic scan, 1-stage double-buffer lookahead ----
    float s = (chunk >= W_TILES) ? 0.47f * x1 : 0.0f;   // attractor / exact-0
    float aps = 0.f, apc = 0.f, qps = 0.f, qpc = 0.f;

    auto rdst = [&](f32x4 (&q)[8], int st) {
        const int col = lane + (st >> 4);
        const int rp0 = 8 * (st & 15);
        #pragma unroll
        for (int u = 0; u < 8; ++u) q[u] = tile[(rp0 + u) * SPAN + col];
    };
    auto wst = [&](f32x4 (&q)[8]) {
        #pragma unroll
        for (int u = 0; u < 8; ++u) stepk(s, q[u], gma);
    };
    auto mst = [&](f32x4 (&q)[8], int st) {
        float psv[8], pcv[8], sv[8];
        #pragma unroll
        for (int u = 0; u < 8; ++u) {
            stepk_m(s, q[u], gma, psv[u], pcv[u]);
            sv[u] = s;
        }
        #pragma unroll
        for (int u = 0; u < 8; ++u) {
            aps += psv[u]; apc += pcv[u];
            qps = fmaf(psv[u], psv[u], qps); qpc = fmaf(pcv[u], pcv[u], qpc);
        }
        const int mb = st - WU_STAGE;
        const size_t pb = (size_t)chunk * 64 + 4 * mb;
        pspc4[pb + 0] = (f32x4){psv[0], pcv[0], psv[1], pcv[1]};
        pspc4[pb + 1] = (f32x4){psv[2], pcv[2], psv[3], pcv[3]};
        pspc4[pb + 2] = (f32x4){psv[4], pcv[4], psv[5], pcv[5]};
        pspc4[pb + 3] = (f32x4){psv[6], pcv[6], psv[7], pcv[7]};
        const size_t sb = (size_t)chunk * 32 + 2 * mb;
        s4[sb]     = (f32x4){sv[0], sv[1], sv[2], sv[3]};
        s4[sb + 1] = (f32x4){sv[4], sv[5], sv[6], sv[7]};
    };

    f32x4 P[8], Q[8];
    rdst(P, 0);
    #pragma unroll 1
    for (int st = 0; st < WU_STAGE; st += 2) {       // stages 0..175
        rdst(Q, st + 1);
        wst(P);
        rdst(P, st + 2);                             // st+2 <= 176 < 192: valid
        wst(Q);
    }
    #pragma unroll 1
    for (int st = WU_STAGE; st < N_STAGE; st += 2) { // stages 176..191
        rdst(Q, st + 1);
        mst(P, st);
        rdst(P, st + 2 < N_STAGE ? st + 2 : N_STAGE - 1);  // clamped dead read
        mst(Q, st + 1);
    }

    // ---- wave reduction (block == 1 wave) of 8 stat accumulators ----
    float vals[8] = {spn, sen, aps, apc, qpn, qen, qps, qpc};
    #pragma unroll
    for (int k = 0; k < 8; ++k) {
        float v = vals[k];
        #pragma unroll
        for (int off = 32; off > 0; off >>= 1) v += __shfl_down(v, off, 64);
        if (lane == 0) partials[b * 8 + k] = v;
    }
}

// ---- stats finalize folded in + fused normalize/assemble ----
__global__ __launch_bounds__(256) void normalize_stats(
        const float* __restrict__ x, const f32x4* __restrict__ pspc4,
        const float* __restrict__ pA, f32x4* __restrict__ out4,
        int nA, int Thalf, int T) {
    __shared__ float red[256];
    __shared__ float sst[8];
    const int tid = threadIdx.x;
    {   // components: 0 pn,1 en,2 ps,3 pc (sums); 4..7 squares
        const int c = tid & 7;
        float v = 0.f;
        for (int i = tid >> 3; i < nA; i += 32) v += pA[i * 8 + c];
        red[tid] = v;
        __syncthreads();
        for (int off = 128; off >= 8; off >>= 1) {
            if (tid < off) red[tid] += red[tid + off];
            __syncthreads();
        }
        if (tid == 0) {
            const float invT = 1.0f / (float)T;
            #pragma unroll
            for (int k = 0; k < 4; ++k) {
                float mu  = red[k] * invT;
                float var = fmaxf(fmaf(-mu, mu, red[4 + k] * invT), 0.0f);
                sst[k]     = mu;
                sst[4 + k] = (var > 0.0f) ? rsqrtf(var) : 0.0f;
            }
        }
        __syncthreads();
    }
    const float mu0 = sst[0], mu1 = sst[1], mu2 = sst[2], mu3 = sst[3];
    const float is0 = sst[4], is1 = sst[5], is2 = sst[6], is3 = sst[7];
    const f32x4* __restrict__ x4 = (const f32x4*)x;
    for (int i = blockIdx.x * 256 + tid; i < Thalf; i += 1024 * 256) {
        f32x4 xv = x4[i];
        f32x4 pq = pspc4[i];
        float d0 = xv.x - xv.y, d1 = xv.z - xv.w;
        out4[2 * i]     = (f32x4){(fmaxf(d0, 0.f) - mu0) * is0,
                                  (fmaxf(-d0, 0.f) - mu1) * is1,
                                  (pq.x - mu2) * is2,
                                  (pq.y - mu3) * is3};
        out4[2 * i + 1] = (f32x4){(fmaxf(d1, 0.f) - mu0) * is0,
                                  (fmaxf(-d1, 0.f) - mu1) * is1,
                                  (pq.z - mu2) * is2,
                                  (pq.w - mu3) * is3};
    }
}

// ---------------- round-1 fallback (proven; own WARMUP=2048, s0=0) ----------
#define FB_WARMUP 2048
__device__ __forceinline__ float inv1p_fb(float a) {
    float i1 = 1.0f - a;
    float i2 = fmaf(-a, i1, 1.0f);
    return fmaf(-a, i2, 1.0f);
}
struct SCfb { float x1, inv_x1, c49; };
__device__ __forceinline__ void scan_step_fb(float& s, float P, float E, const SCfb c,
                                             float& pn, float& en, float& ps, float& pc) {
    float d = P - E;
    float pn_ = fmaxf(d, 0.0f), en_ = fmaxf(-d, 0.0f);
    float up = pn_ * c.inv_x1;
    float tp = up * fmaf(up * up, -(1.0f / 3.0f), 1.0f);
    float un = en_ * c.inv_x1;
    float tn = un * fmaf(un * un, -(1.0f / 3.0f), 1.0f);
    float r = s * c.inv_x1;
    float ps_ = (tp * c.x1) * fmaf(-r, r, 1.0f) * inv1p_fb(r * tp);
    float es_ = (s * (2.0f - r)) * tn * inv1p_fb((1.0f - r) * tn);
    float s1 = s + ps_ - es_;
    float z = s1 * c.c49, z2 = z * z, v = z2 * z2;
    float t = fmaf(v, fmaf(v, 0.15625f, -0.25f), 1.0f);
    float s2 = s1 * t;
    pn = pn_; en = en_; ps = ps_; pc = s1 - s2; s = s2;
}
__global__ __launch_bounds__(256) void scan_kernel_fb(
        const float* __restrict__ x, const float* __restrict__ x1ptr,
        float* __restrict__ out, float* __restrict__ s_store,
        float* __restrict__ partials, int T) {
    const int c = blockIdx.x * blockDim.x + threadIdx.x;
    const int nchunks = (T + L_CHUNK - 1) / L_CHUNK;
    SCfb cc; cc.x1 = x1ptr[0]; cc.inv_x1 = 1.0f / cc.x1; cc.c49 = (4.0f / 9.0f) * cc.inv_x1;
    float s1a[4] = {0.f, 0.f, 0.f, 0.f};
    float s2a[4] = {0.f, 0.f, 0.f, 0.f};
    if (c < nchunks) {
        const int g0 = c * L_CHUNK;
        const int g1 = min(g0 + L_CHUNK, T);
        const int w0 = max(g0 - FB_WARMUP, 0);
        float s = 0.0f; float pn, en, ps, pc;
        const float2* __restrict__ x2 = (const float2*)x;
        for (int t = w0; t < g0; ++t) { float2 xv = x2[t]; scan_step_fb(s, xv.x, xv.y, cc, pn, en, ps, pc); }
        float4* __restrict__ out4 = (float4*)out;
        for (int t = g0; t < g1; ++t) {
            float2 xv = x2[t];
            scan_step_fb(s, xv.x, xv.y, cc, pn, en, ps, pc);
            out4[t] = make_float4(pn, en, ps, pc);
            s_store[t] = s;
            s1a[0] += pn; s1a[1] += en; s1a[2] += ps; s1a[3] += pc;
            s2a[0] = fmaf(pn, pn, s2a[0]); s2a[1] = fmaf(en, en, s2a[1]);
            s2a[2] = fmaf(ps, ps, s2a[2]); s2a[3] = fmaf(pc, pc, s2a[3]);
        }
    }
    __shared__ float red[256];
    float vals[8] = {s1a[0], s1a[1], s1a[2], s1a[3], s2a[0], s2a[1], s2a[2], s2a[3]};
    for (int k = 0; k < 8; ++k) {
        red[threadIdx.x] = vals[k];
        __syncthreads();
        for (int off = 128; off > 0; off >>= 1) {
            if ((int)threadIdx.x < off) red[threadIdx.x] += red[threadIdx.x + off];
            __syncthreads();
        }
        if (threadIdx.x == 0) partials[blockIdx.x * 8 + k] = red[0];
        __syncthreads();
    }
}
__global__ __launch_bounds__(64) void finalize_fb(
        const float* __restrict__ partials, float* __restrict__ stats, int nblk, int T) {
    const int lane = threadIdx.x;
    float v[8] = {0.f, 0.f, 0.f, 0.f, 0.f, 0.f, 0.f, 0.f};
    for (int b = lane; b < nblk; b += 64)
        for (int k = 0; k < 8; ++k) v[k] += partials[b * 8 + k];
    #pragma unroll
    for (int k = 0; k < 8; ++k)
        for (int off = 32; off > 0; off >>= 1) v[k] += __shfl_down(v[k], off, 64);
    if (lane == 0) {
        const float invT = 1.0f / (float)T;
        for (int k = 0; k < 4; ++k) {
            float mu = v[k] * invT;
            float var = fmaxf(fmaf(-mu, mu, v[k + 4] * invT), 0.0f);
            stats[k] = mu;
            stats[4 + k] = (var > 0.0f) ? rsqrtf(var) : 0.0f;
        }
    }
}
__global__ __launch_bounds__(256) void normalize_fb(
        float* __restrict__ out, const float* __restrict__ stats, int T) {
    const int t = blockIdx.x * blockDim.x + threadIdx.x;
    if (t >= T) return;
    const float4 mu = *(const float4*)stats;
    const float4 is = *(const float4*)(stats + 4);
    float4* o4 = (float4*)out;
    float4 v = o4[t];
    v.x = (v.x - mu.x) * is.x; v.y = (v.y - mu.y) * is.y;
    v.z = (v.z - mu.z) * is.z; v.w = (v.w - mu.w) * is.w;
    o4[t] = v;
}
// -----------------------------------------------------------------------------

extern "C" void kernel_launch(void* const* d_in, const int* in_sizes, int n_in,
                              void* d_out, int out_size, void* d_ws, size_t ws_size,
                              hipStream_t stream) {
    const float* x  = (const float*)d_in[0];
    const float* x1 = (const float*)d_in[1];
    const int T = in_sizes[0] / 2;

    float* out     = (float*)d_out;                // (T,4)
    float* s_store = out + 4 * (size_t)T;          // (T,)

    const int C  = T / L_CHUNK;                    // chunks
    const int nA = C / 64;                         // scan blocks (fast path)

    float* pA = (float*)d_ws;                      // nA*8 floats (<=2048)
    const size_t pq_off = 2048;                    // f32x4-aligned float offset
    const size_t need = (pq_off + 2 * (size_t)T) * sizeof(float);

    const bool fast = (T % L_CHUNK == 0) && (C % 64 == 0) &&
                      (T >= WARMUP + L_CHUNK) && (ws_size >= need);

    if (fast) {
        f32x4* pspc4 = (f32x4*)((float*)d_ws + pq_off);
        scan_poly<<<nA, 64, 0, stream>>>(x, x1, pspc4, (f32x4*)s_store, pA);
        const int Thalf = T / 2;
        normalize_stats<<<1024, 256, 0, stream>>>(x, pspc4, pA,
                                                  (f32x4*)out, nA, Thalf, T);
    } else {
        float* stats    = (float*)d_ws;
        float* partials = stats + 8;
        const int nchunks = (T + L_CHUNK - 1) / L_CHUNK;
        const int nblkA = (nchunks + 255) / 256;
        scan_kernel_fb<<<nblkA, 256, 0, stream>>>(x, x1, out, s_store, partials, T);
        finalize_fb<<<1, 64, 0, stream>>>(partials, stats, nblkA, T);
        normalize_fb<<<(T + 255) / 256, 256, 0, stream>>>(out, stats, T);
    }
}